// Round 1
// baseline (117.729 us; speedup 1.0000x reference)
//
#include <hip/hip_runtime.h>

// Bilateral slicing (HDRNet).
// grid  : [B=8][C=12][D=8][Hg=16][Wg=16] fp32  (logical [B,Hg,Wg,D,C] after ref transpose)
// guide : [B=8][1][H=1024][W=1024] fp32 in [0,1)
// out   : [B=8][C=12][H=1024][W=1024] fp32

#define BB 8
#define CC 12
#define DD 8
#define HG 16
#define WG 16
#define HH 1024
#define WW 1024

__global__ __launch_bounds__(1024) void slice_kernel(
    const float* __restrict__ grid,
    const float* __restrict__ guide,
    float* __restrict__ out)
{
    // LDS: y-pre-interpolated grid slice for this row: [c][xg][z], z contiguous
    __shared__ float g2[CC * WG * DD];  // 1536 floats = 6 KB

    const int y   = blockIdx.x;   // 0..1023
    const int b   = blockIdx.y;   // 0..7
    const int tid = threadIdx.x;  // 0..1023 == x

    // ---- y interpolation (block-uniform), clamped-base form ----
    // gy = (y+0.5)*Hg/H; yb = clamp(floor(gy-0.5),0,Hg-2); wy1 = clamp(gy-0.5-yb,0,1)
    const float gy  = ((float)y + 0.5f) * (1.0f / 64.0f);
    const float ty  = gy - 0.5f;
    const int   yb  = (int)fminf(fmaxf(floorf(ty), 0.0f), (float)(HG - 2));
    const float wy1 = fminf(fmaxf(ty - (float)yb, 0.0f), 1.0f);
    const float wy0 = 1.0f - wy1;

    // ---- stage grid into LDS with y pre-applied ----
    const float* gb = grid + (size_t)b * (CC * DD * HG * WG);
    for (int i = tid; i < CC * WG * DD; i += 1024) {
        const int c  = i >> 7;        // /128
        const int r  = i & 127;
        const int xg = r >> 3;        // /8
        const int z  = r & 7;
        const float* p = gb + ((size_t)(c * DD + z)) * (HG * WG) + yb * WG + xg;
        g2[i] = wy0 * p[0] + wy1 * p[WG];
    }
    __syncthreads();

    // ---- per-pixel work ----
    const int x = tid;
    const float g  = guide[((size_t)b * HH + y) * WW + x];

    // z interpolation, clamped-base form
    const float gz  = g * 8.0f;
    const float tz  = gz - 0.5f;
    const int   zb  = (int)fminf(fmaxf(floorf(tz), 0.0f), (float)(DD - 2));
    const float wz1 = fminf(fmaxf(tz - (float)zb, 0.0f), 1.0f);
    const float wz0 = 1.0f - wz1;

    // x interpolation, clamped-base form
    const float gx  = ((float)x + 0.5f) * (1.0f / 64.0f);
    const float tx  = gx - 0.5f;
    const int   xb  = (int)fminf(fmaxf(floorf(tx), 0.0f), (float)(WG - 2));
    const float wx1 = fminf(fmaxf(tx - (float)xb, 0.0f), 1.0f);
    const float wx0 = 1.0f - wx1;

    const float w00 = wx0 * wz0;  // (xb,   zb)
    const float w01 = wx0 * wz1;  // (xb,   zb+1)
    const float w10 = wx1 * wz0;  // (xb+1, zb)
    const float w11 = wx1 * wz1;  // (xb+1, zb+1)

    const int a0 = xb * DD + zb;                 // within-channel word offset
    float* outp = out + ((size_t)(b * CC) * HH + y) * WW + x;

    #pragma unroll
    for (int c = 0; c < CC; ++c) {
        const float* base = g2 + c * (WG * DD);
        // two ds_read2_b32-style pairs (z, z+1) at xb and xb+1
        const float va0 = base[a0];
        const float va1 = base[a0 + 1];
        const float vb0 = base[a0 + DD];
        const float vb1 = base[a0 + DD + 1];
        const float r = w00 * va0 + w01 * va1 + w10 * vb0 + w11 * vb1;
        outp[(size_t)c * (HH * WW)] = r;
    }
}

extern "C" void kernel_launch(void* const* d_in, const int* in_sizes, int n_in,
                              void* d_out, int out_size, void* d_ws, size_t ws_size,
                              hipStream_t stream) {
    const float* grid  = (const float*)d_in[0];  // 8*12*8*16*16
    const float* guide = (const float*)d_in[1];  // 8*1*1024*1024
    float* out = (float*)d_out;                  // 8*12*1024*1024

    dim3 grd(HH, BB);
    dim3 blk(1024);
    slice_kernel<<<grd, blk, 0, stream>>>(grid, guide, out);
}

// Round 2
// 94.554 us; speedup vs baseline: 1.2451x; 1.2451x over previous
//
#include <hip/hip_runtime.h>

// Bilateral slicing (HDRNet).
// grid  : [B=8][C=12][D=8][Hg=16][Wg=16] fp32  (logical [B,Hg,Wg,D,C] after ref transpose)
// guide : [B=8][1][H=1024][W=1024] fp32 in [0,1)
// out   : [B=8][C=12][H=1024][W=1024] fp32

#define BB 8
#define CC 12
#define DD 8
#define HG 16
#define WG 16
#define HH 1024
#define WW 1024

__global__ __launch_bounds__(256) void slice_kernel(
    const float* __restrict__ grid,
    const float* __restrict__ guide,
    float* __restrict__ out)
{
    // LDS: y-pre-interpolated grid slice for this row: [c][xg][z], z contiguous
    __shared__ float g2[CC * WG * DD];  // 1536 floats = 6 KB

    const int y   = blockIdx.x;   // 0..1023
    const int b   = blockIdx.y;   // 0..7
    const int tid = threadIdx.x;  // 0..255

    // ---- y interpolation (block-uniform), clamped-base form ----
    const float gy  = ((float)y + 0.5f) * (1.0f / 64.0f);
    const float ty  = gy - 0.5f;
    const int   yb  = (int)fminf(fmaxf(floorf(ty), 0.0f), (float)(HG - 2));
    const float wy1 = fminf(fmaxf(ty - (float)yb, 0.0f), 1.0f);
    const float wy0 = 1.0f - wy1;

    // ---- stage grid into LDS with y pre-applied (6 full iterations, no divergence) ----
    const float* gb = grid + (size_t)b * (CC * DD * HG * WG);
    #pragma unroll
    for (int k = 0; k < 6; ++k) {
        const int i  = tid + k * 256;
        const int c  = i >> 7;        // /128
        const int r  = i & 127;
        const int xg = r >> 3;        // /8
        const int z  = r & 7;
        const float* p = gb + ((size_t)(c * DD + z)) * (HG * WG) + yb * WG + xg;
        g2[i] = wy0 * p[0] + wy1 * p[WG];
    }
    __syncthreads();

    // ---- per-thread: 4 consecutive pixels, float4 I/O ----
    const int x0 = tid * 4;
    const float4 g4 = *(const float4*)(guide + ((size_t)b * HH + y) * WW + x0);
    const float gvals[4] = {g4.x, g4.y, g4.z, g4.w};

    float w00[4], w01[4], w10[4], w11[4];
    int a0[4];
    #pragma unroll
    for (int p = 0; p < 4; ++p) {
        // z interpolation, clamped-base form
        const float gz  = gvals[p] * 8.0f;
        const float tz  = gz - 0.5f;
        const int   zb  = (int)fminf(fmaxf(floorf(tz), 0.0f), (float)(DD - 2));
        const float wz1 = fminf(fmaxf(tz - (float)zb, 0.0f), 1.0f);
        const float wz0 = 1.0f - wz1;

        // x interpolation, clamped-base form
        const float gx  = ((float)(x0 + p) + 0.5f) * (1.0f / 64.0f);
        const float tx  = gx - 0.5f;
        const int   xb  = (int)fminf(fmaxf(floorf(tx), 0.0f), (float)(WG - 2));
        const float wx1 = fminf(fmaxf(tx - (float)xb, 0.0f), 1.0f);
        const float wx0 = 1.0f - wx1;

        w00[p] = wx0 * wz0;  // (xb,   zb)
        w01[p] = wx0 * wz1;  // (xb,   zb+1)
        w10[p] = wx1 * wz0;  // (xb+1, zb)
        w11[p] = wx1 * wz1;  // (xb+1, zb+1)
        a0[p]  = xb * DD + zb;
    }

    float* outp = out + ((size_t)(b * CC) * HH + y) * WW + x0;

    #pragma unroll
    for (int c = 0; c < CC; ++c) {
        const float* base = g2 + c * (WG * DD);
        float r[4];
        #pragma unroll
        for (int p = 0; p < 4; ++p) {
            const float va0 = base[a0[p]];
            const float va1 = base[a0[p] + 1];
            const float vb0 = base[a0[p] + DD];
            const float vb1 = base[a0[p] + DD + 1];
            r[p] = w00[p] * va0 + w01[p] * va1 + w10[p] * vb0 + w11[p] * vb1;
        }
        const float4 o = make_float4(r[0], r[1], r[2], r[3]);
        *(float4*)(outp + (size_t)c * (HH * WW)) = o;
    }
}

extern "C" void kernel_launch(void* const* d_in, const int* in_sizes, int n_in,
                              void* d_out, int out_size, void* d_ws, size_t ws_size,
                              hipStream_t stream) {
    const float* grid  = (const float*)d_in[0];  // 8*12*8*16*16
    const float* guide = (const float*)d_in[1];  // 8*1*1024*1024
    float* out = (float*)d_out;                  // 8*12*1024*1024

    dim3 grd(HH, BB);
    dim3 blk(256);
    slice_kernel<<<grd, blk, 0, stream>>>(grid, guide, out);
}